// Round 1
// baseline (765.755 us; speedup 1.0000x reference)
//
#include <hip/hip_runtime.h>

// ---------------------------------------------------------------------------
// TransformerBlock: out = LN( FFN(X) + X ),  X = LN( Q + softmax(QK^T/s) V )
// B=32, SQ=SK=D=1024.  bf16 MFMA GEMMs (fp32 accum), fp32 softmax/LN.
// ---------------------------------------------------------------------------

typedef __attribute__((ext_vector_type(8))) short bf16x8;
typedef __attribute__((ext_vector_type(4))) float f32x4;

__device__ __forceinline__ unsigned short f2bf(float f) {
  union { float f; unsigned u; } x; x.f = f;
  unsigned r = x.u + 0x7fffu + ((x.u >> 16) & 1u);  // round-to-nearest-even
  return (unsigned short)(r >> 16);
}

// ---------------- cast f32 -> bf16 (vectorized, grid-stride) ----------------
__global__ __launch_bounds__(256) void cast_kernel(const float* __restrict__ in,
                                                   unsigned short* __restrict__ out,
                                                   long n) {
  long stride = (long)gridDim.x * blockDim.x * 4;
  for (long e = ((long)blockIdx.x * blockDim.x + threadIdx.x) * 4; e < n; e += stride) {
    float4 v = *(const float4*)(in + e);
    ushort4 o;
    o.x = f2bf(v.x); o.y = f2bf(v.y); o.z = f2bf(v.z); o.w = f2bf(v.w);
    *(ushort4*)(out + e) = o;
  }
}

// ---------------- per-batch transpose + cast: Vt[b][d][k] = bf16(V[b][k][d]) ----
__global__ __launch_bounds__(256) void transpose_cast_kernel(const float* __restrict__ V,
                                                             unsigned short* __restrict__ Vt) {
  __shared__ unsigned short tile[32][33];
  const int b = blockIdx.z;
  const float* Vb = V + (size_t)b * 1024 * 1024;
  unsigned short* Vtb = Vt + (size_t)b * 1024 * 1024;
  const int d0 = blockIdx.x * 32, k0 = blockIdx.y * 32;
  const int c = threadIdx.x & 31, rq = threadIdx.x >> 5;
#pragma unroll
  for (int i = 0; i < 4; ++i) {
    int r = rq * 4 + i;
    tile[r][c] = f2bf(Vb[(size_t)(k0 + r) * 1024 + d0 + c]);
  }
  __syncthreads();
#pragma unroll
  for (int i = 0; i < 4; ++i) {
    int r = rq * 4 + i;
    Vtb[(size_t)(d0 + r) * 1024 + k0 + c] = tile[c][r];
  }
}

// ---------------- GEMM: C = A @ B^T  (A:[M][K], B:[N][K] row-major bf16) ----
// 128x128 tile, BK=32, 4 waves (2x2), 4x4 16x16x32 MFMA frags per wave.
// Double-buffered LDS staged with global_load_lds width=16 (2-phase template).
// EPI: 0 = C_f32 = acc*scale ; 2 = C_bf16 = relu(acc+bias) ; 3 = C_f32 = acc+bias
template <int EPI>
__global__ __launch_bounds__(256) void gemm_bt(
    const unsigned short* __restrict__ A, const unsigned short* __restrict__ B,
    const float* __restrict__ bias, void* __restrict__ Cout,
    int M, int N, int K, long sA, long sB, long sC, float scale) {

  __shared__ unsigned short ldsA[2][128 * 32];
  __shared__ unsigned short ldsB[2][128 * 32];

  const int bz = blockIdx.z;
  A += (size_t)bz * sA;
  B += (size_t)bz * sB;
  const size_t cbase = (size_t)bz * sC;

  const int brow = blockIdx.y * 128;
  const int bcol = blockIdx.x * 128;
  const int tid = threadIdx.x;
  const int wave = tid >> 6;
  const int lane = tid & 63;
  const int lr = lane & 15;   // A-row / B-col within 16x16 frag
  const int kh = lane >> 4;   // k-halfword group (8 bf16 each)
  const int wrow = (wave >> 1) * 64;
  const int wcol = (wave & 1) * 64;

  // staging: thread covers row (i*64 + wave*16 + lane/4), cols (lane&3)*8 .. +8
  const int srow = wave * 16 + (lane >> 2);
  const int scol = (lane & 3) * 8;

  f32x4 acc[4][4];
#pragma unroll
  for (int m = 0; m < 4; ++m)
#pragma unroll
    for (int n = 0; n < 4; ++n)
#pragma unroll
      for (int i = 0; i < 4; ++i) acc[m][n][i] = 0.f;

  auto stage = [&](const unsigned short* g, int rowbase, int k0, unsigned short* lds) {
#pragma unroll
    for (int i = 0; i < 2; ++i) {
      const unsigned short* src = g + (size_t)(rowbase + i * 64 + srow) * K + k0 + scol;
      unsigned short* dst = lds + i * 2048 + wave * 512;  // wave-uniform base
      __builtin_amdgcn_global_load_lds(
          (const __attribute__((address_space(1))) void*)src,
          (__attribute__((address_space(3))) void*)dst, 16, 0, 0);
    }
  };

  const int nkt = K >> 5;
  stage(A, brow, 0, ldsA[0]);
  stage(B, bcol, 0, ldsB[0]);
  __syncthreads();  // drains vmcnt(0) before barrier

  int cur = 0;
  for (int kt = 0; kt < nkt; ++kt) {
    if (kt + 1 < nkt) {
      stage(A, brow, (kt + 1) * 32, ldsA[cur ^ 1]);
      stage(B, bcol, (kt + 1) * 32, ldsB[cur ^ 1]);
    }
    bf16x8 af[4], bfr[4];
#pragma unroll
    for (int m = 0; m < 4; ++m)
      af[m] = *(const bf16x8*)&ldsA[cur][(wrow + m * 16 + lr) * 32 + kh * 8];
#pragma unroll
    for (int n = 0; n < 4; ++n)
      bfr[n] = *(const bf16x8*)&ldsB[cur][(wcol + n * 16 + lr) * 32 + kh * 8];
#pragma unroll
    for (int m = 0; m < 4; ++m)
#pragma unroll
      for (int n = 0; n < 4; ++n)
        acc[m][n] = __builtin_amdgcn_mfma_f32_16x16x32_bf16(af[m], bfr[n], acc[m][n], 0, 0, 0);
    __syncthreads();  // next tile staged + everyone done reading cur
    cur ^= 1;
  }

  // epilogue: C[row=(lane>>4)*4+i][col=lane&15] per fragment (m89/m91 layout)
#pragma unroll
  for (int m = 0; m < 4; ++m) {
#pragma unroll
    for (int n = 0; n < 4; ++n) {
      const int c0 = bcol + wcol + n * 16 + lr;
#pragma unroll
      for (int i = 0; i < 4; ++i) {
        const int r0 = brow + wrow + m * 16 + kh * 4 + i;
        float v = acc[m][n][i];
        if (EPI == 0) {
          ((float*)Cout)[cbase + (size_t)r0 * N + c0] = v * scale;
        } else if (EPI == 2) {
          v += bias[c0];
          v = fmaxf(v, 0.f);
          ((unsigned short*)Cout)[cbase + (size_t)r0 * N + c0] = f2bf(v);
        } else {
          v += bias[c0];
          ((float*)Cout)[cbase + (size_t)r0 * N + c0] = v;
        }
      }
    }
  }
}

// ---------------- row softmax: P_bf16 = softmax(S_f32 row of 1024) ----------
__global__ __launch_bounds__(256) void softmax_kernel(const float* __restrict__ S,
                                                      unsigned short* __restrict__ P) {
  __shared__ float red[4];
  const size_t row = blockIdx.x;
  const int t = threadIdx.x;
  float4 v = *(const float4*)(S + row * 1024 + t * 4);
  float mx = fmaxf(fmaxf(v.x, v.y), fmaxf(v.z, v.w));
#pragma unroll
  for (int o = 32; o; o >>= 1) mx = fmaxf(mx, __shfl_xor(mx, o));
  if ((t & 63) == 0) red[t >> 6] = mx;
  __syncthreads();
  mx = fmaxf(fmaxf(red[0], red[1]), fmaxf(red[2], red[3]));
  __syncthreads();
  float e0 = __expf(v.x - mx), e1 = __expf(v.y - mx);
  float e2 = __expf(v.z - mx), e3 = __expf(v.w - mx);
  float s = e0 + e1 + e2 + e3;
#pragma unroll
  for (int o = 32; o; o >>= 1) s += __shfl_xor(s, o);
  if ((t & 63) == 0) red[t >> 6] = s;
  __syncthreads();
  s = red[0] + red[1] + red[2] + red[3];
  const float inv = 1.f / s;
  ushort4 o4;
  o4.x = f2bf(e0 * inv); o4.y = f2bf(e1 * inv);
  o4.z = f2bf(e2 * inv); o4.w = f2bf(e3 * inv);
  *(ushort4*)(P + row * 1024 + t * 4) = o4;
}

// ---------------- fused add + LayerNorm over rows of 1024 -------------------
// out = LN(A + Bv); writes fp32 (Xf) and/or bf16 (Xb). In-place safe (A==Xf).
__global__ __launch_bounds__(256) void add_ln_kernel(
    const float* __restrict__ A, const float* __restrict__ Bv,
    const float* __restrict__ gamma, const float* __restrict__ beta,
    float* __restrict__ Xf, unsigned short* __restrict__ Xb) {
  __shared__ float red[4];
  const size_t row = blockIdx.x;
  const int t = threadIdx.x;
  float4 va = *(const float4*)(A + row * 1024 + t * 4);
  float4 vb = *(const float4*)(Bv + row * 1024 + t * 4);
  float x0 = va.x + vb.x, x1 = va.y + vb.y, x2 = va.z + vb.z, x3 = va.w + vb.w;
  float s = x0 + x1 + x2 + x3;
  float q = x0 * x0 + x1 * x1 + x2 * x2 + x3 * x3;
#pragma unroll
  for (int o = 32; o; o >>= 1) { s += __shfl_xor(s, o); q += __shfl_xor(q, o); }
  if ((t & 63) == 0) red[t >> 6] = s;
  __syncthreads();
  s = red[0] + red[1] + red[2] + red[3];
  __syncthreads();
  if ((t & 63) == 0) red[t >> 6] = q;
  __syncthreads();
  q = red[0] + red[1] + red[2] + red[3];
  const float mu = s * (1.f / 1024.f);
  const float var = q * (1.f / 1024.f) - mu * mu;
  const float rs = rsqrtf(var + 1e-5f);
  float4 g = *(const float4*)(gamma + t * 4);
  float4 be = *(const float4*)(beta + t * 4);
  float o0 = (x0 - mu) * rs * g.x + be.x;
  float o1 = (x1 - mu) * rs * g.y + be.y;
  float o2 = (x2 - mu) * rs * g.z + be.z;
  float o3 = (x3 - mu) * rs * g.w + be.w;
  if (Xf) {
    float4 o; o.x = o0; o.y = o1; o.z = o2; o.w = o3;
    *(float4*)(Xf + row * 1024 + t * 4) = o;
  }
  if (Xb) {
    ushort4 u; u.x = f2bf(o0); u.y = f2bf(o1); u.z = f2bf(o2); u.w = f2bf(o3);
    *(ushort4*)(Xb + row * 1024 + t * 4) = u;
  }
}

// ---------------------------------------------------------------------------
extern "C" void kernel_launch(void* const* d_in, const int* in_sizes, int n_in,
                              void* d_out, int out_size, void* d_ws, size_t ws_size,
                              hipStream_t stream) {
  const float* Q    = (const float*)d_in[0];
  const float* Km   = (const float*)d_in[1];
  const float* V    = (const float*)d_in[2];
  const float* W1   = (const float*)d_in[3];
  const float* b1   = (const float*)d_in[4];
  const float* W2   = (const float*)d_in[5];
  const float* b2   = (const float*)d_in[6];
  const float* gamma = (const float*)d_in[7];
  const float* beta  = (const float*)d_in[8];
  float* out = (float*)d_out;

  // workspace layout (bytes):
  //  [0, 64M)      Qb bf16            (later reused as P bf16)
  //  [64M, 128M)   Kb bf16            (later reused as Hb bf16)
  //  [128M, 192M)  Vtb bf16           (later reused as Xb bf16)
  //  [192M, 320M)  S  fp32 scores     (later reused as VA fp32)
  //  [320M, 448M)  X  fp32 (LN1 out)
  //  [448M, ...)   W1b, W2b bf16
  char* ws = (char*)d_ws;
  const size_t NEL = (size_t)32 * 1024 * 1024;  // 33,554,432 elements
  unsigned short* Qb  = (unsigned short*)ws;
  unsigned short* Kb  = Qb + NEL;
  unsigned short* Vtb = Kb + NEL;
  float* S = (float*)(ws + 3 * NEL * 2);
  float* X = (float*)(ws + 3 * NEL * 2 + NEL * 4);
  unsigned short* W1b = (unsigned short*)(ws + 3 * NEL * 2 + 2 * NEL * 4);
  unsigned short* W2b = W1b + 1024 * 1024;
  unsigned short* P  = Qb;   // alias: Qb dead after GEMM1
  float*          VA = S;    // alias: S dead after softmax
  unsigned short* Xb = Vtb;  // alias: Vtb dead after GEMM2
  unsigned short* Hb = Kb;   // alias: Kb dead after GEMM1

  const long M1 = 1024L * 1024L;  // per-batch stride (elements)
  const float scale = 1.0f / (sqrtf(1024.0f) + 1e-8f);

  cast_kernel<<<4096, 256, 0, stream>>>(Q, Qb, (long)NEL);
  cast_kernel<<<4096, 256, 0, stream>>>(Km, Kb, (long)NEL);
  cast_kernel<<<64, 256, 0, stream>>>(W1, W1b, 1024 * 1024);
  cast_kernel<<<64, 256, 0, stream>>>(W2, W2b, 1024 * 1024);
  transpose_cast_kernel<<<dim3(32, 32, 32), 256, 0, stream>>>(V, Vtb);

  // S = (Q K^T) * scale            [per-batch 1024x1024x1024]
  gemm_bt<0><<<dim3(8, 8, 32), 256, 0, stream>>>(Qb, Kb, nullptr, S,
                                                 1024, 1024, 1024, M1, M1, M1, scale);
  // P = softmax(S) -> bf16
  softmax_kernel<<<32768, 256, 0, stream>>>(S, P);
  // VA = P @ V  (= P @ Vt^T)
  gemm_bt<0><<<dim3(8, 8, 32), 256, 0, stream>>>(P, Vtb, nullptr, VA,
                                                 1024, 1024, 1024, M1, M1, M1, 1.0f);
  // X = LN(Q + VA)  (fp32 X for residual, bf16 Xb for FFN)
  add_ln_kernel<<<32768, 256, 0, stream>>>(Q, VA, gamma, beta, X, Xb);
  // Hb = relu(Xb @ W1^T + b1) -> bf16     [32768 x 1024 x 1024]
  gemm_bt<2><<<dim3(8, 256, 1), 256, 0, stream>>>(Xb, W1b, b1, Hb,
                                                  32768, 1024, 1024, 0, 0, 0, 1.0f);
  // out = Hb @ W2^T + b2 (fp32, into d_out as scratch)
  gemm_bt<3><<<dim3(8, 256, 1), 256, 0, stream>>>(Hb, W2b, b2, out,
                                                  32768, 1024, 1024, 0, 0, 0, 1.0f);
  // out = LN(out + X)   (in-place)
  add_ln_kernel<<<32768, 256, 0, stream>>>(out, X, gamma, beta, out, nullptr);
}

// Round 2
// 644.554 us; speedup vs baseline: 1.1880x; 1.1880x over previous
//
#include <hip/hip_runtime.h>

// ---------------------------------------------------------------------------
// TransformerBlock: out = LN( FFN(X) + X ),  X = LN( Q + softmax(QK^T/s) V )
// B=32, SQ=SK=D=1024.  bf16 MFMA GEMMs (fp32 accum, 256^2 8-phase schedule),
// fp32 softmax/LN.
// ---------------------------------------------------------------------------

typedef __attribute__((ext_vector_type(8))) short bf16x8;
typedef __attribute__((ext_vector_type(4))) float f32x4;

__device__ __forceinline__ unsigned short f2bf(float f) {
  union { float f; unsigned u; } x; x.f = f;
  unsigned r = x.u + 0x7fffu + ((x.u >> 16) & 1u);  // round-to-nearest-even
  return (unsigned short)(r >> 16);
}

// ---------------- cast f32 -> bf16 (vectorized, grid-stride) ----------------
__global__ __launch_bounds__(256) void cast_kernel(const float* __restrict__ in,
                                                   unsigned short* __restrict__ out,
                                                   long n) {
  long stride = (long)gridDim.x * blockDim.x * 4;
  for (long e = ((long)blockIdx.x * blockDim.x + threadIdx.x) * 4; e < n; e += stride) {
    float4 v = *(const float4*)(in + e);
    ushort4 o;
    o.x = f2bf(v.x); o.y = f2bf(v.y); o.z = f2bf(v.z); o.w = f2bf(v.w);
    *(ushort4*)(out + e) = o;
  }
}

// ---------------- per-batch transpose + cast: Vt[b][d][k] = bf16(V[b][k][d]) ----
__global__ __launch_bounds__(256) void transpose_cast_kernel(const float* __restrict__ V,
                                                             unsigned short* __restrict__ Vt) {
  __shared__ unsigned short tile[32][33];
  const int b = blockIdx.z;
  const float* Vb = V + (size_t)b * 1024 * 1024;
  unsigned short* Vtb = Vt + (size_t)b * 1024 * 1024;
  const int d0 = blockIdx.x * 32, k0 = blockIdx.y * 32;
  const int c = threadIdx.x & 31, rq = threadIdx.x >> 5;
#pragma unroll
  for (int i = 0; i < 4; ++i) {
    int r = rq * 4 + i;
    tile[r][c] = f2bf(Vb[(size_t)(k0 + r) * 1024 + d0 + c]);
  }
  __syncthreads();
#pragma unroll
  for (int i = 0; i < 4; ++i) {
    int r = rq * 4 + i;
    Vtb[(size_t)(d0 + r) * 1024 + k0 + c] = tile[c][r];
  }
}

// ---------------------------------------------------------------------------
// GEMM: C = A @ B^T  (A:[M][K], B:[N][K] row-major bf16, K multiple of 128)
// 256x256 tile, BK=64, 8 waves (2Mx4N), 8-phase schedule, counted vmcnt(4),
// T2 XOR-swizzle ((row&7)<<4) both-sides, T5 setprio, T1 XCD swizzle.
// EPI: 0 = C_f32 = acc*scale ; 2 = C_bf16 = relu(acc+bias) ; 3 = C_f32 = acc+bias
// ---------------------------------------------------------------------------
template <int EPI>
__global__ __launch_bounds__(512, 2) void gemm8(
    const unsigned short* __restrict__ A, const unsigned short* __restrict__ B,
    const float* __restrict__ bias, void* __restrict__ Cout,
    int N, int K, long sA, long sB, long sC, float scale, int gx, int gxy) {

  __shared__ unsigned short ldsA[2][16384];  // [buf][256 rows x 64 cols]
  __shared__ unsigned short ldsB[2][16384];

  // bijective XCD swizzle (nwg % 8 == 0 guaranteed by launcher)
  const int nwg = gridDim.x;
  const int orig = blockIdx.x;
  const int wg = (orig & 7) * (nwg >> 3) + (orig >> 3);
  const int bz = wg / gxy;
  const int rem = wg - bz * gxy;
  const int by = rem / gx;
  const int bx = rem - by * gx;

  A += (size_t)bz * sA;
  B += (size_t)bz * sB;
  const size_t cbase = (size_t)bz * sC;
  const int brow = by * 256, bcol = bx * 256;

  const int tid = threadIdx.x;
  const int wave = tid >> 6, lane = tid & 63;
  const int wm = wave >> 2, wn = wave & 3;   // 2 x 4 wave grid
  const int lr = lane & 15, kh = lane >> 4;
  const int swz = (lane & 7) << 4;           // (row&7)<<4 — row&7 == lane&7 for frag reads

  // staging: per call (8KB) lane covers row wave*8+(lane>>3), pre-swizzled col
  const int s_r = wave * 8 + (lane >> 3);
  const int s_c = ((lane & 7) ^ (lane >> 3)) * 8;

  auto stg = [&](const unsigned short* g, int rowbase, int kt, int h,
                 unsigned short* region) {
#pragma unroll
    for (int j = 0; j < 2; ++j) {
      const unsigned short* src =
          g + (size_t)(rowbase + h * 128 + j * 64 + s_r) * K + kt * 64 + s_c;
      unsigned short* dst = region + h * 8192 + j * 4096 + wave * 512;  // wave-uniform
      __builtin_amdgcn_global_load_lds(
          (const __attribute__((address_space(1))) void*)src,
          (__attribute__((address_space(3))) void*)dst, 16, 0, 0);
    }
  };

  auto rdA = [&](int c, int m, int k) -> bf16x8 {
    const int r = wm * 128 + m * 16 + lr;
    const int off = r * 128 + ((k * 64 + kh * 16) ^ swz);
    return *(const bf16x8*)((const char*)ldsA[c] + off);
  };
  auto rdB = [&](int c, int n, int k) -> bf16x8 {
    const int r = wn * 64 + n * 16 + lr;
    const int off = r * 128 + ((k * 64 + kh * 16) ^ swz);
    return *(const bf16x8*)((const char*)ldsB[c] + off);
  };

  f32x4 acc[8][4];
#pragma unroll
  for (int m = 0; m < 8; ++m)
#pragma unroll
    for (int n = 0; n < 4; ++n)
#pragma unroll
      for (int i = 0; i < 4; ++i) acc[m][n][i] = 0.f;

  const int nt = K >> 6;   // K-tiles of 64
  const int nI = nt >> 1;  // 2 tiles per iteration

  // prologue: A(0), B(0), B(1) — 12 loads; leave B(1) (newest 4) in flight
  stg(A, brow, 0, 0, ldsA[0]); stg(A, brow, 0, 1, ldsA[0]);
  stg(B, bcol, 0, 0, ldsB[0]); stg(B, bcol, 0, 1, ldsB[0]);
  stg(B, bcol, 1, 0, ldsB[1]); stg(B, bcol, 1, 1, ldsB[1]);
  asm volatile("s_waitcnt vmcnt(4)" ::: "memory");
  asm volatile("s_barrier" ::: "memory");

  bf16x8 bfrag[4][2];

  for (int I = 0; I < nI; ++I) {
    const bool nl = (I + 1 < nI);
#pragma unroll
    for (int g = 0; g < 2; ++g) {          // tile group: tile t = 2I+g in buf g
#pragma unroll
      for (int q = 0; q < 4; ++q) {        // quadrant: A-frags m = 2q, 2q+1
        const int p = g * 4 + q;

        // ---- ds_read register subtile ----
        if (q == 0) {
#pragma unroll
          for (int n = 0; n < 4; ++n)
#pragma unroll
            for (int k = 0; k < 2; ++k) bfrag[n][k] = rdB(g, n, k);
        }
        bf16x8 afr[2][2];
#pragma unroll
        for (int mm = 0; mm < 2; ++mm)
#pragma unroll
          for (int k = 0; k < 2; ++k) afr[mm][k] = rdA(g, q * 2 + mm, k);

        // ---- stage schedule (regions freed >=1 barrier earlier; see proof) ----
        if (p == 0) stg(A, brow, 2 * I + 1, 0, ldsA[1]);
        if (p == 1) { stg(A, brow, 2 * I + 1, 1, ldsA[1]);
                      if (nl) stg(B, bcol, 2 * I + 2, 0, ldsB[0]); }
        if (p == 2) { if (nl) stg(B, bcol, 2 * I + 2, 1, ldsB[0]); }
        if (p == 4) { if (nl) stg(A, brow, 2 * I + 2, 0, ldsA[0]); }
        if (p == 5) { if (nl) stg(A, brow, 2 * I + 2, 1, ldsA[0]); }
        if (p == 6) { if (nl) stg(B, bcol, 2 * I + 3, 0, ldsB[1]); }
        if (p == 7) { if (nl) stg(B, bcol, 2 * I + 3, 1, ldsB[1]); }

        asm volatile("s_barrier" ::: "memory");  // barrier1 (no vmem drain)

        __builtin_amdgcn_s_setprio(1);
#pragma unroll
        for (int mm = 0; mm < 2; ++mm)
#pragma unroll
          for (int n = 0; n < 4; ++n)
#pragma unroll
            for (int k = 0; k < 2; ++k)
              acc[q * 2 + mm][n] = __builtin_amdgcn_mfma_f32_16x16x32_bf16(
                  afr[mm][k], bfrag[n][k], acc[q * 2 + mm][n], 0, 0, 0);
        __builtin_amdgcn_s_setprio(0);

        // counted waits once per K-tile (phases 4 & 8); drain on final tile-pair
        if (q == 3) {
          if (g == 0 && !nl) asm volatile("s_waitcnt vmcnt(0)" ::: "memory");
          else               asm volatile("s_waitcnt vmcnt(4)" ::: "memory");
        }
        asm volatile("s_barrier" ::: "memory");  // barrier2
      }
    }
  }

  // epilogue: C[row=(lane>>4)*4+i][col=lane&15] per 16x16 fragment
#pragma unroll
  for (int m = 0; m < 8; ++m) {
#pragma unroll
    for (int n = 0; n < 4; ++n) {
      const int c0 = bcol + wn * 64 + n * 16 + lr;
#pragma unroll
      for (int i = 0; i < 4; ++i) {
        const int r0 = brow + wm * 128 + m * 16 + kh * 4 + i;
        float v = acc[m][n][i];
        if (EPI == 0) {
          ((float*)Cout)[cbase + (size_t)r0 * N + c0] = v * scale;
        } else if (EPI == 2) {
          v += bias[c0];
          v = fmaxf(v, 0.f);
          ((unsigned short*)Cout)[cbase + (size_t)r0 * N + c0] = f2bf(v);
        } else {
          v += bias[c0];
          ((float*)Cout)[cbase + (size_t)r0 * N + c0] = v + 0.f;
        }
      }
    }
  }
}

// ---------------- row softmax: P_bf16 = softmax(S_f32 row of 1024) ----------
__global__ __launch_bounds__(256) void softmax_kernel(const float* __restrict__ S,
                                                      unsigned short* __restrict__ P) {
  __shared__ float red[4];
  const size_t row = blockIdx.x;
  const int t = threadIdx.x;
  float4 v = *(const float4*)(S + row * 1024 + t * 4);
  float mx = fmaxf(fmaxf(v.x, v.y), fmaxf(v.z, v.w));
#pragma unroll
  for (int o = 32; o; o >>= 1) mx = fmaxf(mx, __shfl_xor(mx, o));
  if ((t & 63) == 0) red[t >> 6] = mx;
  __syncthreads();
  mx = fmaxf(fmaxf(red[0], red[1]), fmaxf(red[2], red[3]));
  __syncthreads();
  float e0 = __expf(v.x - mx), e1 = __expf(v.y - mx);
  float e2 = __expf(v.z - mx), e3 = __expf(v.w - mx);
  float s = e0 + e1 + e2 + e3;
#pragma unroll
  for (int o = 32; o; o >>= 1) s += __shfl_xor(s, o);
  if ((t & 63) == 0) red[t >> 6] = s;
  __syncthreads();
  s = red[0] + red[1] + red[2] + red[3];
  const float inv = 1.f / s;
  ushort4 o4;
  o4.x = f2bf(e0 * inv); o4.y = f2bf(e1 * inv);
  o4.z = f2bf(e2 * inv); o4.w = f2bf(e3 * inv);
  *(ushort4*)(P + row * 1024 + t * 4) = o4;
}

// ---------------- fused add + LayerNorm over rows of 1024 -------------------
__global__ __launch_bounds__(256) void add_ln_kernel(
    const float* __restrict__ A, const float* __restrict__ Bv,
    const float* __restrict__ gamma, const float* __restrict__ beta,
    float* __restrict__ Xf, unsigned short* __restrict__ Xb) {
  __shared__ float red[4];
  const size_t row = blockIdx.x;
  const int t = threadIdx.x;
  float4 va = *(const float4*)(A + row * 1024 + t * 4);
  float4 vb = *(const float4*)(Bv + row * 1024 + t * 4);
  float x0 = va.x + vb.x, x1 = va.y + vb.y, x2 = va.z + vb.z, x3 = va.w + vb.w;
  float s = x0 + x1 + x2 + x3;
  float q = x0 * x0 + x1 * x1 + x2 * x2 + x3 * x3;
#pragma unroll
  for (int o = 32; o; o >>= 1) { s += __shfl_xor(s, o); q += __shfl_xor(q, o); }
  if ((t & 63) == 0) red[t >> 6] = s;
  __syncthreads();
  s = red[0] + red[1] + red[2] + red[3];
  __syncthreads();
  if ((t & 63) == 0) red[t >> 6] = q;
  __syncthreads();
  q = red[0] + red[1] + red[2] + red[3];
  const float mu = s * (1.f / 1024.f);
  const float var = q * (1.f / 1024.f) - mu * mu;
  const float rs = rsqrtf(var + 1e-5f);
  float4 g = *(const float4*)(gamma + t * 4);
  float4 be = *(const float4*)(beta + t * 4);
  float o0 = (x0 - mu) * rs * g.x + be.x;
  float o1 = (x1 - mu) * rs * g.y + be.y;
  float o2 = (x2 - mu) * rs * g.z + be.z;
  float o3 = (x3 - mu) * rs * g.w + be.w;
  if (Xf) {
    float4 o; o.x = o0; o.y = o1; o.z = o2; o.w = o3;
    *(float4*)(Xf + row * 1024 + t * 4) = o;
  }
  if (Xb) {
    ushort4 u; u.x = f2bf(o0); u.y = f2bf(o1); u.z = f2bf(o2); u.w = f2bf(o3);
    *(ushort4*)(Xb + row * 1024 + t * 4) = u;
  }
}

// ---------------------------------------------------------------------------
extern "C" void kernel_launch(void* const* d_in, const int* in_sizes, int n_in,
                              void* d_out, int out_size, void* d_ws, size_t ws_size,
                              hipStream_t stream) {
  const float* Q    = (const float*)d_in[0];
  const float* Km   = (const float*)d_in[1];
  const float* V    = (const float*)d_in[2];
  const float* W1   = (const float*)d_in[3];
  const float* b1   = (const float*)d_in[4];
  const float* W2   = (const float*)d_in[5];
  const float* b2   = (const float*)d_in[6];
  const float* gamma = (const float*)d_in[7];
  const float* beta  = (const float*)d_in[8];
  float* out = (float*)d_out;

  char* ws = (char*)d_ws;
  const size_t NEL = (size_t)32 * 1024 * 1024;
  unsigned short* Qb  = (unsigned short*)ws;
  unsigned short* Kb  = Qb + NEL;
  unsigned short* Vtb = Kb + NEL;
  float* S = (float*)(ws + 3 * NEL * 2);
  float* X = (float*)(ws + 3 * NEL * 2 + NEL * 4);
  unsigned short* W1b = (unsigned short*)(ws + 3 * NEL * 2 + 2 * NEL * 4);
  unsigned short* W2b = W1b + 1024 * 1024;
  unsigned short* P  = Qb;   // alias: Qb dead after GEMM1
  float*          VA = S;    // alias: S dead after softmax
  unsigned short* Xb = Vtb;  // alias: Vtb dead after GEMM2
  unsigned short* Hb = Kb;   // alias: Kb dead after GEMM1

  const long M1 = 1024L * 1024L;
  const float scale = 1.0f / (sqrtf(1024.0f) + 1e-8f);

  cast_kernel<<<4096, 256, 0, stream>>>(Q, Qb, (long)NEL);
  cast_kernel<<<4096, 256, 0, stream>>>(Km, Kb, (long)NEL);
  cast_kernel<<<64, 256, 0, stream>>>(W1, W1b, 1024 * 1024);
  cast_kernel<<<64, 256, 0, stream>>>(W2, W2b, 1024 * 1024);
  transpose_cast_kernel<<<dim3(32, 32, 32), 256, 0, stream>>>(V, Vtb);

  // S = (Q K^T) * scale   [32 batches of 1024^3, grid 4x4x32 = 512 blocks]
  gemm8<0><<<512, 512, 0, stream>>>(Qb, Kb, nullptr, S, 1024, 1024, M1, M1, M1, scale, 4, 16);
  softmax_kernel<<<32768, 256, 0, stream>>>(S, P);
  // VA = P @ Vt^T
  gemm8<0><<<512, 512, 0, stream>>>(P, Vtb, nullptr, VA, 1024, 1024, M1, M1, M1, 1.0f, 4, 16);
  add_ln_kernel<<<32768, 256, 0, stream>>>(Q, VA, gamma, beta, X, Xb);
  // Hb = relu(Xb @ W1^T + b1)   [32768x1024x1024, grid 4x128 = 512 blocks]
  gemm8<2><<<512, 512, 0, stream>>>(Xb, W1b, b1, Hb, 1024, 1024, 0, 0, 0, 1.0f, 4, 512);
  // out = Hb @ W2^T + b2 (fp32 scratch in d_out)
  gemm8<3><<<512, 512, 0, stream>>>(Hb, W2b, b2, out, 1024, 1024, 0, 0, 0, 1.0f, 4, 512);
  add_ln_kernel<<<32768, 256, 0, stream>>>(out, X, gamma, beta, out, nullptr);
}